// Round 1
// baseline (213.435 us; speedup 1.0000x reference)
//
#include <hip/hip_runtime.h>
#include <hip/hip_bf16.h>

// LinearAttention_MLP on MI355X.
// Key simplification: k-softmax is over a size-1 axis (==1), so
// s = sum_d softmax(q)_d * SCALE = 0.125 exactly -> out = 0.125*v.
// q/k projections are dead code. Pipeline:
//   v = 0.125 * x @ Wv^T          (Wv = w_qkv rows [1024:1536), already (N,K) layout)
//   y = v @ w_out^T + b_out       (w_out already (N,K) layout)
//   out = y / max(||y||_2, eps) * g * 32

typedef __attribute__((ext_vector_type(8))) short bf16x8;   // 8 bf16 = 4 VGPRs
typedef __attribute__((ext_vector_type(4))) float f32x4;

#define BLK 128
#define BK  32

// ---------------- cast fp32 -> bf16, 8 elems/thread ----------------
struct alignas(16) bfvec8 { __hip_bfloat16 h[8]; };

__global__ __launch_bounds__(256)
void cast_bf16(const float* __restrict__ in, bfvec8* __restrict__ out, int n8) {
    int i = blockIdx.x * blockDim.x + threadIdx.x;
    if (i >= n8) return;
    const float4* p = (const float4*)in + (size_t)i * 2;
    float4 a = p[0];
    float4 b = p[1];
    bfvec8 o;
    o.h[0] = __float2bfloat16(a.x); o.h[1] = __float2bfloat16(a.y);
    o.h[2] = __float2bfloat16(a.z); o.h[3] = __float2bfloat16(a.w);
    o.h[4] = __float2bfloat16(b.x); o.h[5] = __float2bfloat16(b.y);
    o.h[6] = __float2bfloat16(b.z); o.h[7] = __float2bfloat16(b.w);
    out[i] = o;
}

// ---------------- m97-style bf16 GEMM, B given transposed (N,K) ----------------
// C = alpha * A @ Bt^T (+ bias), A: MxK, Bt: NxK, C: MxN.
// 256 threads = 4 waves in 2x2; each wave computes 64x64 via 4x4 frags of 16x16x32.
template<bool WRITE_BF16>
__global__ __launch_bounds__(256)
void gemm_bt(const __hip_bfloat16* __restrict__ A,
             const __hip_bfloat16* __restrict__ Bt,
             void* __restrict__ Cout,
             const float* __restrict__ bias,
             int M, int N, int K, float alpha)
{
    __shared__ __align__(16) __hip_bfloat16 As[BLK * BK];  // [m][k] row-major, 8 KB
    __shared__ __align__(16) __hip_bfloat16 Bs[BLK * BK];  // [n][k] row-major, 8 KB

    const int tid  = threadIdx.x;
    const int lane = tid & 63;
    const int wave = tid >> 6;     // 0..3
    const int wm   = wave >> 1;    // 0..1  (row half)
    const int wn   = wave & 1;     // 0..1  (col half)
    const int quad = lane >> 4;    // 0..3
    const int tr   = lane & 15;    // 0..15

    const int m0 = blockIdx.y * BLK;
    const int n0 = blockIdx.x * BLK;

    f32x4 acc[4][4];
#pragma unroll
    for (int i = 0; i < 4; ++i)
#pragma unroll
        for (int j = 0; j < 4; ++j)
            acc[i][j] = (f32x4){0.f, 0.f, 0.f, 0.f};

    for (int kt = 0; kt < K; kt += BK) {
        // Stage 128x32 bf16 tiles (8 KB each) via async global->LDS, 16 B/lane.
        // L is linear in lane => LDS dest = base + lane*16 (wave-uniform-base rule).
#pragma unroll
        for (int i = 0; i < 2; ++i) {
            int L  = i * 256 + wave * 64 + lane;   // 0..511
            int r  = L >> 2;                       // tile row 0..127
            int c8 = (L & 3) << 3;                 // k-offset {0,8,16,24}
            const __hip_bfloat16* ga = A  + (size_t)(m0 + r) * K + kt + c8;
            const __hip_bfloat16* gb = Bt + (size_t)(n0 + r) * K + kt + c8;
            __builtin_amdgcn_global_load_lds(
                (const __attribute__((address_space(1))) void*)ga,
                (__attribute__((address_space(3))) void*)(As + (size_t)L * 8), 16, 0, 0);
            __builtin_amdgcn_global_load_lds(
                (const __attribute__((address_space(1))) void*)gb,
                (__attribute__((address_space(3))) void*)(Bs + (size_t)L * 8), 16, 0, 0);
        }
        __syncthreads();   // compiler emits vmcnt(0) drain before barrier

        bf16x8 af[4], bf[4];
#pragma unroll
        for (int mi = 0; mi < 4; ++mi)
            af[mi] = *(const bf16x8*)(As + ((wm * 64 + mi * 16 + tr) * BK + quad * 8));
#pragma unroll
        for (int ni = 0; ni < 4; ++ni)
            bf[ni] = *(const bf16x8*)(Bs + ((wn * 64 + ni * 16 + tr) * BK + quad * 8));

#pragma unroll
        for (int mi = 0; mi < 4; ++mi)
#pragma unroll
            for (int ni = 0; ni < 4; ++ni)
                acc[mi][ni] = __builtin_amdgcn_mfma_f32_16x16x32_bf16(
                    af[mi], bf[ni], acc[mi][ni], 0, 0, 0);

        __syncthreads();
    }

    // Epilogue. C/D layout: col = lane&15, row = quad*4 + reg.
#pragma unroll
    for (int mi = 0; mi < 4; ++mi) {
#pragma unroll
        for (int ni = 0; ni < 4; ++ni) {
            const int col = n0 + wn * 64 + ni * 16 + tr;
            float b = 0.f;
            if (!WRITE_BF16 && bias != nullptr) b = bias[col];
#pragma unroll
            for (int r = 0; r < 4; ++r) {
                const int row = m0 + wm * 64 + mi * 16 + quad * 4 + r;
                float val = acc[mi][ni][r] * alpha + b;
                if (WRITE_BF16)
                    ((__hip_bfloat16*)Cout)[(size_t)row * N + col] = __float2bfloat16(val);
                else
                    ((float*)Cout)[(size_t)row * N + col] = val;
            }
        }
    }
}

// ---------------- in-place per-row RMS norm: y = y / max(||y||,eps) * g * 32 ----------------
__global__ __launch_bounds__(256)
void rmsnorm_rows(float* __restrict__ y, const float* __restrict__ g) {
    const int row = blockIdx.x;
    const int tid = threadIdx.x;
    float* p = y + (size_t)row * 1024 + tid * 4;
    float4 v = *(float4*)p;
    float ss = v.x * v.x + v.y * v.y + v.z * v.z + v.w * v.w;
#pragma unroll
    for (int off = 32; off > 0; off >>= 1)
        ss += __shfl_down(ss, off, 64);
    __shared__ float wsum[4];
    if ((tid & 63) == 0) wsum[tid >> 6] = ss;
    __syncthreads();
    const float total = wsum[0] + wsum[1] + wsum[2] + wsum[3];
    const float sc = 32.0f / fmaxf(sqrtf(total), 1e-12f);
    const float4 gv = *(const float4*)(g + tid * 4);
    v.x *= sc * gv.x; v.y *= sc * gv.y; v.z *= sc * gv.z; v.w *= sc * gv.w;
    *(float4*)p = v;
}

extern "C" void kernel_launch(void* const* d_in, const int* in_sizes, int n_in,
                              void* d_out, int out_size, void* d_ws, size_t ws_size,
                              hipStream_t stream) {
    const float* x     = (const float*)d_in[0];   // (16384, 1024)
    const float* w_qkv = (const float*)d_in[1];   // (1536, 1024)
    const float* w_out = (const float*)d_in[2];   // (1024, 512)
    const float* b_out = (const float*)d_in[3];   // (1024,)
    const float* g     = (const float*)d_in[4];   // (1, 1024)

    const int B = 16384, D = 1024, H = 512;

    char* ws = (char*)d_ws;
    __hip_bfloat16* x_bf  = (__hip_bfloat16*)ws;                                   // B*D bf16, 32 MB
    __hip_bfloat16* wv_bf = (__hip_bfloat16*)(ws + (size_t)B * D * 2);             // H*D bf16, 1 MB
    __hip_bfloat16* wo_bf = (__hip_bfloat16*)(ws + (size_t)B * D * 2 + (size_t)H * D * 2);           // D*H
    __hip_bfloat16* v_bf  = (__hip_bfloat16*)(ws + (size_t)B * D * 2 + (size_t)H * D * 2 * 2);       // B*H, 16 MB

    // 1) casts to bf16
    cast_bf16<<<(B * D / 8) / 256, 256, 0, stream>>>(x, (bfvec8*)x_bf, B * D / 8);
    cast_bf16<<<(H * D / 8) / 256, 256, 0, stream>>>(w_qkv + (size_t)2 * H * D, (bfvec8*)wv_bf, H * D / 8);
    cast_bf16<<<(D * H / 8) / 256, 256, 0, stream>>>(w_out, (bfvec8*)wo_bf, D * H / 8);

    // 2) v = 0.125 * x @ Wv^T   (M=B, N=H, K=D) -> bf16
    gemm_bt<true><<<dim3(H / BLK, B / BLK), 256, 0, stream>>>(
        x_bf, wv_bf, (void*)v_bf, nullptr, B, H, D, 0.125f);

    // 3) y = v @ w_out^T + b_out  (M=B, N=D, K=H) -> fp32 into d_out
    gemm_bt<false><<<dim3(D / BLK, B / BLK), 256, 0, stream>>>(
        v_bf, wo_bf, d_out, b_out, B, D, H, 1.0f);

    // 4) in-place row norm
    rmsnorm_rows<<<B, 256, 0, stream>>>((float*)d_out, g);
}